// Round 7
// baseline (316.856 us; speedup 1.0000x reference)
//
#include <hip/hip_runtime.h>
#include <math.h>

#define NPn 30000
#define EPn 480000
#define NLl 48
#define ELl 144
#define Tn 96
#define NAn 11
#define Dn 256
#define N1 49
#define NEGf (-1000000000.0f)
#define NSTATES 97
#define CHN 125
#define PC 13            // P columns: [g | u(4) | v(4) | hmean(4)]
#define YN (N1*PC)       // 637

// ================= kernel A: deg atomics | sim (packed phases) | lig | pre =================

__global__ __launch_bounds__(256) void kA(
    const int* __restrict__ dst_p, int* __restrict__ deg,
    const int* __restrict__ lab_in, const int* __restrict__ bfs_i, const int* __restrict__ bfs_b,
    int* __restrict__ lab_idx, float* __restrict__ lab_means,
    int* __restrict__ dirs, int* __restrict__ dird, float* __restrict__ m_arr,
    float* __restrict__ e_arr, int* __restrict__ rec, int* __restrict__ Sout,
    const float* __restrict__ xg, const int* __restrict__ srcl, const int* __restrict__ dstl,
    const float* __restrict__ Wl1, const float* __restrict__ bl1,
    const float* __restrict__ Wl2, const float* __restrict__ bl2, float* __restrict__ zl_mean,
    const float* __restrict__ Wd2, const float* __restrict__ Wg, const float* __restrict__ Wh,
    float* __restrict__ Pm){
  const int bid = blockIdx.x;
  const int tid = threadIdx.x;

  if (bid == 0){
    // ---------- control sim: packed ctrl, no cross-lane latency chains ----------
    __shared__ int sv[Tn], sb[Tn];
    __shared__ int qarr[Tn+1];
    __shared__ int2 ctrl[Tn];        // x: u | doe<<8 | pop<<9 | act<<10 | timec<<16 ; y: v | bix<<8
    __shared__ float valuA[Tn], valvA[Tn];
    __shared__ float baseB[Tn][N1];
    __shared__ int slab[N1];
    __shared__ int cntL[NAn];
    if (tid < Tn){ sv[tid]=bfs_i[2*tid+1]; sb[tid]=bfs_b[tid]; }
    if (tid <= Tn) qarr[tid]=0;
    if (tid < NAn) cntL[tid]=0;
    if (tid < N1){ int l=(tid<NLl)? lab_in[tid] : (NAn-1); slab[tid]=l; lab_idx[tid]=l; }
    __syncthreads();
    if (tid < NLl) atomicAdd(&cntL[slab[tid]],1);
    if (tid == 0) qarr[0]=bfs_i[0];
    __syncthreads();
    if (tid < NAn){
      int c=cntL[tid];
      lab_means[tid]     = ((float)c + ((tid==NAn-1)?1.f:0.f))*(1.0f/49.0f);
      lab_means[NAn+tid] = (float)c*(1.0f/48.0f);
    }
    // ---- phase 0: scalar control recurrence (bfs-only deps), incl. u ----
    if (tid == 0){
      dirs[192]=qarr[0]; dird[192]=bfs_i[1];
      int head=0, tail=1, ec=0, timec=0;
      for (int t=0;t<Tn;t++){
        int v = sv[t], bix = sb[t];
        int active = (tail>head)?1:0;
        int h = (head<=Tn)? head : Tn;
        int u = qarr[h];
        int is_stop = (v==NLl)?1:0;
        int pop = active & is_stop;
        int doe = active & (is_stop^1);
        ctrl[t] = make_int2(u | (doe<<8) | (pop<<9) | (active<<10) | (timec<<16), v | (bix<<8));
        if (doe){
          if (tail<=Tn) qarr[tail]=v;
          if (ec<192){ dirs[ec]=u; dird[ec]=v; dirs[ec+1]=v; dird[ec+1]=u; }
        }
        head+=pop; tail+=doe; ec+=2*doe; timec+=doe;
      }
      Sout[0]=ec/2;
    }
    __syncthreads();
    // ---- phase 0.5: rec outputs (parallel over t) ----
    if (tid < Tn){
      int2 c=ctrl[tid];
      rec[tid]=c.x&255; rec[Tn+tid]=c.y&255; rec[2*Tn+tid]=(c.y>>8)&3;
      rec[3*Tn+tid]=(c.x>>10)&1; rec[4*Tn+tid]=(c.x>>8)&1; rec[5*Tn+tid]=(c.x>>16)&255;
    }
    __syncthreads();
    // ---- phase A: per-lane val/closed/adj recurrence; 1 packed LDS read/iter ----
    if (tid < 64){
      const int l = tid;
      int labv = (l<N1)? slab[l] : (NAn-1);
      float val;
      switch(labv){
        case 0: val=4.f; break; case 1: val=1.f; break; case 2: val=3.f; break;
        case 3: val=1.f; break; case 4: val=2.f; break; case 5: val=1.f; break;
        case 6: val=5.f; break; case 7: val=1.f; break; case 8: val=6.f; break;
        case 9: val=1.f; break; default: val=1000.f; break;
      }
      if (l>=N1) val=0.f;
      int closed=0;
      unsigned long long adjm=0ull;
      #pragma unroll 4
      for (int t=0;t<Tn;t++){
        int2 c=ctrl[t];
        int u=c.x&255, doe=(c.x>>8)&1, pop=(c.x>>9)&1;
        int v=c.y&255, bix=(c.y>>8)&3;
        float base = (val<1.f || closed || ((adjm>>u)&1ull)) ? NEGf : 0.f;
        if (l==u) base=NEGf;
        if (l<N1) baseB[t][l]=base;
        if (l==u) valuA[t]=val;
        if (l==v) valvA[t]=val;
        if (doe){
          float dec = (bix==0)?1.f:(bix==1)?2.f:(bix==2)?3.f:1.5f;
          if (l==u){ val-=dec; adjm |= (1ull<<v); }
          if (l==v){ val-=dec; adjm |= (1ull<<u); }
        }
        if (pop && l==u) closed=1;
      }
    }
    __syncthreads();
    // ---- phase B: finalize m/e outputs ----
    {
      const int lane=tid&63, wv=tid>>6;
      for (int t=wv; t<Tn; t+=4){
        float valu=valuA[t], valv=valvA[t];
        int v=sv[t], bix=sb[t];
        if (lane<N1){
          float mnou = (valu<1.f)? NEGf : baseB[t][lane];
          float m = mnou;
          if (lane==v) m=0.f;
          if (lane==NLl) m=0.f;
          m_arr[t*N1+lane]=m;
        }
        if (lane<4){
          float mnv = (valu<1.f)? NEGf : baseB[t][v];
          float mv = fminf(valu,valv);
          float e;
          if (mv<=0.f) e=NEGf;
          else if (mv<=1.f) e=((lane==1)||(lane==2))?NEGf:0.f;
          else if (mv<=2.f) e=(lane==2)?NEGf:0.f;
          else e=0.f;
          if (mnv <= NEGf*0.5f) e=NEGf;
          if (lane==bix) e=0.f;
          e_arr[t*4+lane]=e;
        }
      }
    }
    return;
  }

  if (bid == 1){
    // ---------- ligand GCN mean (collapsed, vectorized) ----------
    __shared__ float sW[15*Dn];
    __shared__ __align__(16) float sagg[NLl][16];   // [0..3]=geom*dinv_s, [4..14]=label*dinv_s, [15]=pad
    __shared__ float ow[NLl];
    __shared__ float rs[Dn];
    __shared__ float sdinv[NLl];
    __shared__ int sdeg[NLl];
    __shared__ int ses[ELl], sed[ELl];
    __shared__ int slab2[NLl];
    if (tid<NLl){ sdeg[tid]=1; slab2[tid]=lab_in[tid]; }
    for (int i=tid;i<NLl*16;i+=256) sagg[i>>4][i&15]=0.f;
    for (int i=tid;i<15*Dn;i+=256) sW[i]=Wl1[i];
    __syncthreads();
    if (tid<ELl){ ses[tid]=srcl[tid]; sed[tid]=dstl[tid]; atomicAdd(&sdeg[dstl[tid]],1); }
    __syncthreads();
    if (tid<NLl) sdinv[tid]=rsqrtf((float)sdeg[tid]);
    __syncthreads();
    if (tid<NLl){
      float dv=sdinv[tid];
      ow[tid]=dv;
      for (int q=0;q<4;q++) sagg[tid][q]=xg[tid*4+q]*dv;
      sagg[tid][4+slab2[tid]]=dv;
    }
    __syncthreads();
    if (tid<ELl){
      int s=ses[tid], d=sed[tid];
      float dvs=sdinv[s];
      for (int q=0;q<4;q++) atomicAdd(&sagg[d][q], xg[s*4+q]*dvs);
      atomicAdd(&sagg[d][4+slab2[s]], dvs);
      atomicAdd(&ow[s], sdinv[d]);
    }
    __syncthreads();
    {
      int c=tid;
      float wcol[16];
      #pragma unroll
      for (int q=0;q<15;q++) wcol[q]=sW[q*Dn+c];
      wcol[15]=0.f;
      float b=bl1[c];
      float rsum=0.f;
      for (int d=0;d<NLl;d++){
        const float4* ar=(const float4*)sagg[d];
        float4 x0=ar[0],x1=ar[1],x2=ar[2],x3=ar[3];
        float a=0.f;
        a=fmaf(x0.x,wcol[0],a); a=fmaf(x0.y,wcol[1],a); a=fmaf(x0.z,wcol[2],a); a=fmaf(x0.w,wcol[3],a);
        a=fmaf(x1.x,wcol[4],a); a=fmaf(x1.y,wcol[5],a); a=fmaf(x1.z,wcol[6],a); a=fmaf(x1.w,wcol[7],a);
        a=fmaf(x2.x,wcol[8],a); a=fmaf(x2.y,wcol[9],a); a=fmaf(x2.z,wcol[10],a); a=fmaf(x2.w,wcol[11],a);
        a=fmaf(x3.x,wcol[12],a); a=fmaf(x3.y,wcol[13],a); a=fmaf(x3.z,wcol[14],a);
        float h=fmaxf(sdinv[d]*a + b, 0.f);
        rsum = fmaf(sdinv[d]*ow[d], h, rsum);
      }
      rs[c]=rsum*(1.0f/48.0f);
    }
    __syncthreads();
    {
      int c=tid;
      float a=0.f;
      for (int k=0;k<Dn;k++) a=fmaf(rs[k], Wl2[(size_t)k*Dn+c], a);
      zl_mean[c]=a+bl2[c];
    }
    return;
  }

  if (bid < 2+64){
    // ---------- P = Wd2 @ [wg2 | Whu | Whv | Whh] : one k per wave ----------
    const int lane = tid&63, wv = tid>>6;
    const int k = (bid-2)*4 + wv;
    float pg=0.f;
    float4 pu=make_float4(0,0,0,0), pv=make_float4(0,0,0,0), ph=make_float4(0,0,0,0);
    for (int q=0;q<4;q++){
      int n = lane + 64*q;
      float w = Wd2[(size_t)k*Dn+n];
      pg = fmaf(w, Wg[524+n], pg);
      float4 a=*(const float4*)&Wh[(size_t)(257+n)*4];
      float4 b=*(const float4*)&Wh[(size_t)(524+n)*4];
      float4 c=*(const float4*)&Wh[(size_t)(791+n)*4];
      pu.x=fmaf(w,a.x,pu.x); pu.y=fmaf(w,a.y,pu.y); pu.z=fmaf(w,a.z,pu.z); pu.w=fmaf(w,a.w,pu.w);
      pv.x=fmaf(w,b.x,pv.x); pv.y=fmaf(w,b.y,pv.y); pv.z=fmaf(w,b.z,pv.z); pv.w=fmaf(w,b.w,pv.w);
      ph.x=fmaf(w,c.x,ph.x); ph.y=fmaf(w,c.y,ph.y); ph.z=fmaf(w,c.z,ph.z); ph.w=fmaf(w,c.w,ph.w);
    }
    for (int off=32; off>0; off>>=1){
      pg += __shfl_xor(pg,off);
      pu.x+=__shfl_xor(pu.x,off); pu.y+=__shfl_xor(pu.y,off); pu.z+=__shfl_xor(pu.z,off); pu.w+=__shfl_xor(pu.w,off);
      pv.x+=__shfl_xor(pv.x,off); pv.y+=__shfl_xor(pv.y,off); pv.z+=__shfl_xor(pv.z,off); pv.w+=__shfl_xor(pv.w,off);
      ph.x+=__shfl_xor(ph.x,off); ph.y+=__shfl_xor(ph.y,off); ph.z+=__shfl_xor(ph.z,off); ph.w+=__shfl_xor(ph.w,off);
    }
    if (lane==0){
      float* o = Pm + k*PC;
      o[0]=pg; o[1]=pu.x; o[2]=pu.y; o[3]=pu.z; o[4]=pu.w;
      o[5]=pv.x; o[6]=pv.y; o[7]=pv.z; o[8]=pv.w;
      o[9]=ph.x; o[10]=ph.y; o[11]=ph.z; o[12]=ph.w;
    }
    return;
  }

  // ---------- deg atomics ----------
  {
    int e = (bid-66)*256 + tid;
    if (e < EPn) atomicAdd(&deg[dst_p[e]], 1);
  }
}

// ================= prep: rowptr scan (block 0) | xp16 pad (blocks 1..) =================

__global__ __launch_bounds__(1024) void k_prep(const int* __restrict__ deg, const float* __restrict__ xp,
    int* __restrict__ rowptr, int* __restrict__ cursor, float* __restrict__ xp16){
  if (blockIdx.x == 0){
    __shared__ int part[1024];
    const int t = threadIdx.x;
    const int base = t*30;
    int loc[30];
    int s=0;
    #pragma unroll
    for (int i=0;i<30;i++){
      int idx=base+i;
      int v=(idx<NPn)? deg[idx] : 0;
      loc[i]=s; s+=v;
    }
    part[t]=s;
    __syncthreads();
    for (int off=1; off<1024; off<<=1){
      int x = (t>=off)? part[t-off] : 0;
      __syncthreads();
      part[t]+=x;
      __syncthreads();
    }
    int excl = part[t]-s;
    #pragma unroll
    for (int i=0;i<30;i++){
      int idx=base+i;
      if (idx<NPn){ int rp=excl+loc[i]; rowptr[idx]=rp; cursor[idx]=rp; }
    }
    if (t==1023) rowptr[NPn]=part[1023];
    return;
  }
  // pad: xp16[r][c<15] = x_p[r][c]*dinv_r ; [15] = dinv_r
  int r = (blockIdx.x-1)*64 + (threadIdx.x>>4), c = threadIdx.x&15;
  if (r < NPn){
    float dv = rsqrtf((float)(deg[r]+1));
    float v = (c<15)? xp[r*15+c]*dv : dv;
    xp16[(size_t)r*16+c]=v;
  }
}

// ================= fill: CSR colidx + odegw =================

__global__ void k_fill(const int* __restrict__ src, const int* __restrict__ dst,
                       const int* __restrict__ deg, int* __restrict__ cursor,
                       int* __restrict__ colidx, float* __restrict__ odegw){
  int e = blockIdx.x*blockDim.x + threadIdx.x;
  if (e >= EPn) return;
  int s = src[e], d = dst[e];
  atomicAdd(&odegw[s], rsqrtf((float)(deg[d]+1)));
  int pos = atomicAdd(&cursor[d], 1);
  colidx[pos] = s;
}

// ================= fuse: gather 15-wide aggregates + matvec + weighted rowsum =================

__global__ __launch_bounds__(256) void k_fuse(const float* __restrict__ xp16,
    const int* __restrict__ deg, const float* __restrict__ odegw,
    const int* __restrict__ rowptr, const int* __restrict__ colidx,
    const float* __restrict__ Wp1, const float* __restrict__ bp1, float* __restrict__ zr){
  __shared__ __align__(16) float sx[CHN][16];
  __shared__ float sc[CHN];
  const int tid = threadIdx.x;
  const int base = blockIdx.x*CHN;
  if (tid < CHN){
    int n = base + tid;          // 240*125 == NPn exactly
    const float4* xr = (const float4*)(xp16 + (size_t)n*16);
    float4 a0=xr[0], a1=xr[1], a2=xr[2], a3=xr[3];   // self (pre-scaled by dinv_n)
    int e0=rowptr[n], e1=rowptr[n+1];
    for (int e=e0;e<e1;e++){
      int s=colidx[e];
      const float4* xs=(const float4*)(xp16 + (size_t)s*16);
      float4 b0=xs[0], b1=xs[1], b2=xs[2], b3=xs[3];
      a0.x+=b0.x; a0.y+=b0.y; a0.z+=b0.z; a0.w+=b0.w;
      a1.x+=b1.x; a1.y+=b1.y; a1.z+=b1.z; a1.w+=b1.w;
      a2.x+=b2.x; a2.y+=b2.y; a2.z+=b2.z; a2.w+=b2.w;
      a3.x+=b3.x; a3.y+=b3.y; a3.z+=b3.z; a3.w+=b3.w;
    }
    float dv = rsqrtf((float)(deg[n]+1));
    a0.x*=dv; a0.y*=dv; a0.z*=dv; a0.w*=dv;
    a1.x*=dv; a1.y*=dv; a1.z*=dv; a1.w*=dv;
    a2.x*=dv; a2.y*=dv; a2.z*=dv; a2.w*=dv;
    a3.x*=dv; a3.y*=dv; a3.z*=dv; a3.w*=dv;
    float4* so=(float4*)sx[tid];
    so[0]=a0; so[1]=a1; so[2]=a2; so[3]=a3;
    sc[tid]=dv*(odegw[n]+dv);
  }
  __syncthreads();
  float wcol[16];
  #pragma unroll
  for (int k=0;k<15;k++) wcol[k]=Wp1[k*Dn+tid];
  wcol[15]=0.f;
  float b = bp1[tid];
  float acc = 0.f;
  for (int i=0;i<CHN;i++){
    const float4* sr=(const float4*)sx[i];
    float4 x0=sr[0],x1=sr[1],x2=sr[2],x3=sr[3];
    float d0=b;
    d0=fmaf(x0.x,wcol[0],d0); d0=fmaf(x0.y,wcol[1],d0); d0=fmaf(x0.z,wcol[2],d0); d0=fmaf(x0.w,wcol[3],d0);
    d0=fmaf(x1.x,wcol[4],d0); d0=fmaf(x1.y,wcol[5],d0); d0=fmaf(x1.z,wcol[6],d0); d0=fmaf(x1.w,wcol[7],d0);
    d0=fmaf(x2.x,wcol[8],d0); d0=fmaf(x2.y,wcol[9],d0); d0=fmaf(x2.z,wcol[10],d0); d0=fmaf(x2.w,wcol[11],d0);
    d0=fmaf(x3.x,wcol[12],d0); d0=fmaf(x3.y,wcol[13],d0); d0=fmaf(x3.z,wcol[14],d0);
    acc = fmaf(sc[i], fmaxf(d0,0.f), acc);
  }
  atomicAdd(&zr[tid], acc);
}

// ================= z_pocket GEMV + hconst (fused) =================

__global__ __launch_bounds__(256) void k_zh(const float* __restrict__ zr, const float* __restrict__ Wp2,
    const float* __restrict__ bp2, const float* __restrict__ zl, const float* __restrict__ lm,
    const float* __restrict__ b2, const float* __restrict__ Wh, const float* __restrict__ bh,
    float* __restrict__ hc4){
  __shared__ float sr[Dn];
  __shared__ float zp[Dn];
  int tid=threadIdx.x;
  sr[tid]=zr[tid]*(1.0f/30000.0f);
  __syncthreads();
  float a=0.f;
  for (int k=0;k<Dn;k++) a=fmaf(sr[k],Wp2[(size_t)k*Dn+tid],a);
  zp[tid]=a+bp2[tid];
  __syncthreads();
  if (tid<64){
    int lane=tid;
    float4 h=make_float4(0,0,0,0);
    for (int q=0;q<4;q++){
      int n=lane+64*q;
      float4 w1=*(const float4*)&Wh[(size_t)(1+n)*4];
      float4 w2=*(const float4*)&Wh[(size_t)(1058+n)*4];
      float4 wu=*(const float4*)&Wh[(size_t)(257+n)*4];
      float4 wv=*(const float4*)&Wh[(size_t)(524+n)*4];
      float4 wh=*(const float4*)&Wh[(size_t)(791+n)*4];
      float zpn=zp[n], zln=zl[n], bn=b2[n];
      h.x += zpn*w1.x + zln*w2.x + bn*(wu.x+wv.x+wh.x);
      h.y += zpn*w1.y + zln*w2.y + bn*(wu.y+wv.y+wh.y);
      h.z += zpn*w1.z + zln*w2.z + bn*(wu.z+wv.z+wh.z);
      h.w += zpn*w1.w + zln*w2.w + bn*(wu.w+wv.w+wh.w);
    }
    if (lane<NAn){
      float4 wa=*(const float4*)&Wh[(size_t)(1047+lane)*4];
      float4 wb=*(const float4*)&Wh[(size_t)(1314+lane)*4];
      float aa=lm[lane], bb=lm[NAn+lane];
      h.x += aa*wa.x + bb*wb.x; h.y += aa*wa.y + bb*wb.y;
      h.z += aa*wa.z + bb*wb.z; h.w += aa*wa.w + bb*wb.w;
    }
    for (int off=32; off>0; off>>=1){
      h.x+=__shfl_xor(h.x,off); h.y+=__shfl_xor(h.y,off);
      h.z+=__shfl_xor(h.z,off); h.w+=__shfl_xor(h.w,off);
    }
    if (lane==0){
      hc4[0]=h.x+bh[0]; hc4[1]=h.y+bh[1]; hc4[2]=h.z+bh[2]; hc4[3]=h.w+bh[3];
    }
  }
}

// ================= decoder state + per-step logp (fused) =================

__global__ __launch_bounds__(256) void k_dc(const int* __restrict__ Sp, const int* __restrict__ dirs,
    const int* __restrict__ dird, const int* __restrict__ lab_idx,
    const float* __restrict__ Wd1, const float* __restrict__ bd1,
    const float* __restrict__ Pm, const int* __restrict__ rec,
    const float* __restrict__ m_arr, const float* __restrict__ e_arr,
    const float* __restrict__ hc4, const float* __restrict__ Wg, const float* __restrict__ Wh,
    float* __restrict__ out){
  int k = blockIdx.x;
  if (k > Sp[0]) return;
  __shared__ float sW[11*Dn];
  __shared__ float sP[Dn*PC];
  __shared__ float hT[Dn*N1];
  __shared__ float cnt[N1*11];
  __shared__ float y1[YN];
  __shared__ float za[YN];
  __shared__ float sdinv[N1];
  __shared__ int sdeg[N1];
  __shared__ int se[192], sd[192];
  __shared__ int slab[N1];
  __shared__ int srec[6*Tn];
  int tid=threadIdx.x;
  int ecnt = (k==0)?1:(2*k);
  int base = (k==0)?192:0;
  if (tid<N1){ sdeg[tid]=1; slab[tid]=lab_idx[tid]; }
  for (int i=tid;i<N1*11;i+=256) cnt[i]=0.f;
  for (int i=tid;i<11*Dn;i+=256) sW[i]=Wd1[i];
  for (int i=tid;i<Dn*PC;i+=256) sP[i]=Pm[i];
  for (int i=tid;i<6*Tn;i+=256) srec[i]=rec[i];
  __syncthreads();
  if (tid<ecnt){ se[tid]=dirs[base+tid]; sd[tid]=dird[base+tid]; atomicAdd(&sdeg[sd[tid]],1); }
  __syncthreads();
  if (tid<N1) sdinv[tid]=rsqrtf((float)sdeg[tid]);
  __syncthreads();
  if (tid<N1) cnt[tid*11+slab[tid]] = sdinv[tid];
  __syncthreads();
  if (tid<ecnt) atomicAdd(&cnt[sd[tid]*11+slab[se[tid]]], sdinv[se[tid]]);
  __syncthreads();
  {
    int c=tid;
    float wreg[11];
    for (int a=0;a<11;a++) wreg[a]=sW[a*Dn+c];
    float b=bd1[c];
    for (int r=0;r<N1;r++){
      float s=0.f;
      for (int a=0;a<11;a++) s=fmaf(cnt[r*11+a], wreg[a], s);
      hT[c*N1+r]=fmaxf(sdinv[r]*s + b, 0.f);
    }
  }
  __syncthreads();
  for (int idx=tid; idx<YN; idx+=256){
    int r=idx/PC, j=idx-r*PC;
    float acc=0.f;
    for (int c=0;c<Dn;c++) acc=fmaf(hT[c*N1+r], sP[c*PC+j], acc);
    y1[idx]=acc;
    za[idx]=sdinv[r]*acc;
  }
  __syncthreads();
  for (int i=tid; i<ecnt*PC; i+=256){
    int e=i/PC, j=i-e*PC;
    atomicAdd(&za[sd[e]*PC+j], sdinv[se[e]]*y1[se[e]*PC+j]);
  }
  __syncthreads();
  for (int idx=tid; idx<YN; idx+=256){
    int r=idx/PC;
    za[idx]=sdinv[r]*za[idx];
  }
  __syncthreads();
  if (tid>=64) return;
  const int lane=tid;
  for (int t=0;t<Tn;t++){
    if (!srec[3*Tn+t] || srec[5*Tn+t]!=k) continue;
    const int u=srec[t], v=srec[Tn+t], bidx=srec[2*Tn+t], doe=srec[4*Tn+t];
    float g = -INFINITY;
    float4 hm = make_float4(0,0,0,0);
    if (lane<N1){
      const float* zrow = za + lane*PC;
      g = zrow[0] + Wg[780+slab[lane]] + m_arr[t*N1+lane];
      hm.x=zrow[9]; hm.y=zrow[10]; hm.z=zrow[11]; hm.w=zrow[12];
    }
    float gv = __shfl(g, v);
    float gM = g;
    for (int off=32; off>0; off>>=1) gM = fmaxf(gM, __shfl_xor(gM, off));
    float ex = (lane<N1)? expf(g-gM) : 0.f;
    float gS = ex;
    for (int off=32; off>0; off>>=1){
      gS += __shfl_xor(gS, off);
      hm.x+=__shfl_xor(hm.x,off); hm.y+=__shfl_xor(hm.y,off);
      hm.z+=__shfl_xor(hm.z,off); hm.w+=__shfl_xor(hm.w,off);
    }
    if (lane==0){
      float res = gv - gM - logf(gS);
      if (doe){
        const int lu=slab[u], lv=slab[v];
        const float tf=(float)k;
        float h[4];
        for (int j=0;j<4;j++){
          float hmj = (j==0)?hm.x:(j==1)?hm.y:(j==2)?hm.z:hm.w;
          h[j] = hc4[j] + tf*Wh[j] + Wh[(513+lu)*4+j] + Wh[(780+lv)*4+j]
               + za[u*PC+1+j] + za[v*PC+5+j] + hmj*(1.0f/49.0f) + e_arr[4*t+j];
        }
        float M=fmaxf(fmaxf(h[0],h[1]),fmaxf(h[2],h[3]));
        float se2=expf(h[0]-M)+expf(h[1]-M)+expf(h[2]-M)+expf(h[3]-M);
        float hb=(bidx==0)?h[0]:(bidx==1)?h[1]:(bidx==2)?h[2]:h[3];
        res += hb - M - logf(se2);
      }
      atomicAdd(out, res);
    }
  }
}

// ================= launch =================

extern "C" void kernel_launch(void* const* d_in, const int* in_sizes, int n_in,
                              void* d_out, int out_size, void* d_ws, size_t ws_size,
                              hipStream_t stream){
  const float* x_p      =(const float*)d_in[0];
  const int*   src_p    =(const int*)d_in[1];
  const int*   dst_p    =(const int*)d_in[2];
  const float* x_l_geom =(const float*)d_in[3];
  const int*   x_l_label=(const int*)d_in[4];
  const int*   src_l    =(const int*)d_in[5];
  const int*   dst_l    =(const int*)d_in[6];
  const int*   bfs_index=(const int*)d_in[7];
  const int*   bfs_bond =(const int*)d_in[8];
  const float* Wp1=(const float*)d_in[9];
  const float* bp1=(const float*)d_in[10];
  const float* Wp2=(const float*)d_in[11];
  const float* bp2=(const float*)d_in[12];
  const float* Wl1=(const float*)d_in[13];
  const float* bl1=(const float*)d_in[14];
  const float* Wl2=(const float*)d_in[15];
  const float* bl2=(const float*)d_in[16];
  const float* Wd1=(const float*)d_in[17];
  const float* bd1=(const float*)d_in[18];
  const float* Wd2=(const float*)d_in[19];
  const float* bd2=(const float*)d_in[20];
  const float* Wg =(const float*)d_in[23];
  const float* Wh =(const float*)d_in[25];
  const float* bh =(const float*)d_in[26];

  char* w=(char*)d_ws;
  size_t off=0;
  auto alloc=[&](size_t bytes)->char*{ char* p=w+off; off=(off+bytes+255)&~((size_t)255); return p; };
  // ---- contiguous zero-init region: deg, odegw, zr ----
  int*   deg    =(int*)alloc((size_t)NPn*4);
  float* odegw  =(float*)alloc((size_t)NPn*4);
  float* zr     =(float*)alloc(Dn*4);
  size_t zero_span = off;
  // ---- rest (fully written before read) ----
  int*   rowptr =(int*)alloc((size_t)(NPn+1)*4);
  int*   cursor =(int*)alloc((size_t)NPn*4);
  int*   colidx =(int*)alloc((size_t)EPn*4);
  float* xp16   =(float*)alloc((size_t)NPn*16*4);
  float* zl_mean=(float*)alloc(Dn*4);
  float* Pm     =(float*)alloc(Dn*PC*4);
  float* hc4    =(float*)alloc(4*4);
  float* m_arr  =(float*)alloc((size_t)Tn*N1*4);
  float* e_arr  =(float*)alloc((size_t)Tn*4*4);
  int*   rec    =(int*)alloc((size_t)6*Tn*4);
  int*   dirs   =(int*)alloc(194*4);
  int*   dird   =(int*)alloc(194*4);
  int*   lab_idx=(int*)alloc(N1*4);
  float* lab_means=(float*)alloc(2*NAn*4);
  int*   Sval   =(int*)alloc(4);
  (void)in_sizes;(void)n_in;(void)ws_size;

  hipMemsetAsync(d_ws, 0, zero_span, stream);
  hipMemsetAsync(d_out, 0, (size_t)out_size*sizeof(float), stream);

  // A: sim (block 0) | lig (block 1) | pre (blocks 2..65) | deg (blocks 66..)
  kA<<<66 + EPn/256, 256, 0, stream>>>(
      dst_p, deg,
      x_l_label, bfs_index, bfs_bond, lab_idx, lab_means, dirs, dird, m_arr, e_arr, rec, Sval,
      x_l_geom, src_l, dst_l, Wl1, bl1, Wl2, bl2, zl_mean,
      Wd2, Wg, Wh, Pm);
  // prep: scan (block 0) | xp16 pad (blocks 1..469)
  k_prep<<<1 + (NPn+63)/64, 1024, 0, stream>>>(deg, x_p, rowptr, cursor, xp16);
  // fill: CSR colidx + odegw
  k_fill<<<(EPn+255)/256, 256, 0, stream>>>(src_p, dst_p, deg, cursor, colidx, odegw);
  // fuse: gather + matvec + weighted rowsum
  k_fuse<<<NPn/CHN, 256, 0, stream>>>(xp16, deg, odegw, rowptr, colidx, Wp1, bp1, zr);
  // z_pocket GEMV + hconst
  k_zh<<<1,256,0,stream>>>(zr,Wp2,bp2,zl_mean,lab_means,bd2,Wh,bh,hc4);
  // decoder states + per-step logp
  k_dc<<<NSTATES,256,0,stream>>>(Sval,dirs,dird,lab_idx,Wd1,bd1,Pm,rec,m_arr,e_arr,hc4,Wg,Wh,(float*)d_out);
}

// Round 8
// 268.669 us; speedup vs baseline: 1.1794x; 1.1794x over previous
//
#include <hip/hip_runtime.h>
#include <math.h>

#define NPn 30000
#define EPn 480000
#define NLl 48
#define ELl 144
#define Tn 96
#define NAn 11
#define Dn 256
#define N1 49
#define NEGf (-1000000000.0f)
#define NSTATES 97
#define CHN 125
#define PC 13            // P columns: [g | u(4) | v(4) | hmean(4)]
#define YN (N1*PC)       // 637

// ================= k_deg: in-degree atomics =================

__global__ void k_deg(const int* __restrict__ dst, int* __restrict__ deg){
  int e = blockIdx.x*blockDim.x + threadIdx.x;
  if (e < EPn) atomicAdd(&deg[dst[e]], 1);
}

// ================= k_mega: sim (b0) | lig (b1) | pre (b2..65) | xagg (b66..) =================

__global__ __launch_bounds__(256) void k_mega(
    // xagg part
    const int* __restrict__ src_p, const int* __restrict__ dst_p, const float* __restrict__ xp,
    const int* __restrict__ deg, float* __restrict__ xagg, float* __restrict__ odegw,
    // sim part
    const int* __restrict__ lab_in, const int* __restrict__ bfs_i, const int* __restrict__ bfs_b,
    int* __restrict__ lab_idx, float* __restrict__ lab_means,
    int* __restrict__ dirs, int* __restrict__ dird, float* __restrict__ m_arr,
    float* __restrict__ e_arr, int* __restrict__ rec, int* __restrict__ Sout,
    // lig part
    const float* __restrict__ xg, const int* __restrict__ srcl, const int* __restrict__ dstl,
    const float* __restrict__ Wl1, const float* __restrict__ bl1,
    const float* __restrict__ Wl2, const float* __restrict__ bl2, float* __restrict__ zl_mean,
    // pre part
    const float* __restrict__ Wd2, const float* __restrict__ Wg, const float* __restrict__ Wh,
    float* __restrict__ Pm){
  const int bid = blockIdx.x;
  const int tid = threadIdx.x;

  if (bid >= 66){
    // ---------- xagg scatter: 16 edges x 16 lanes per block ----------
    int g = (bid-66)*256 + tid;
    int e = g>>4, c = g&15;
    if (e >= EPn) return;
    int s = src_p[e], d = dst_p[e];
    if (c < 15){
      float dvs = rsqrtf((float)(deg[s]+1));
      atomicAdd(&xagg[d*16+c], xp[s*15+c]*dvs);
    } else {
      float dvd = rsqrtf((float)(deg[d]+1));
      atomicAdd(&odegw[s], dvd);
    }
    return;
  }

  if (bid == 0){
    // ---------- control sim: packed ctrl, no cross-lane latency chains ----------
    __shared__ int sv[Tn], sb[Tn];
    __shared__ int qarr[Tn+1];
    __shared__ int2 ctrl[Tn];        // x: u | doe<<8 | pop<<9 | act<<10 | timec<<16 ; y: v | bix<<8
    __shared__ float valuA[Tn], valvA[Tn];
    __shared__ float baseB[Tn][N1];
    __shared__ int slab[N1];
    __shared__ int cntL[NAn];
    if (tid < Tn){ sv[tid]=bfs_i[2*tid+1]; sb[tid]=bfs_b[tid]; }
    if (tid <= Tn) qarr[tid]=0;
    if (tid < NAn) cntL[tid]=0;
    if (tid < N1){ int l=(tid<NLl)? lab_in[tid] : (NAn-1); slab[tid]=l; lab_idx[tid]=l; }
    __syncthreads();
    if (tid < NLl) atomicAdd(&cntL[slab[tid]],1);
    if (tid == 0) qarr[0]=bfs_i[0];
    __syncthreads();
    if (tid < NAn){
      int c=cntL[tid];
      lab_means[tid]     = ((float)c + ((tid==NAn-1)?1.f:0.f))*(1.0f/49.0f);
      lab_means[NAn+tid] = (float)c*(1.0f/48.0f);
    }
    // ---- phase 0: scalar control recurrence ----
    if (tid == 0){
      dirs[192]=qarr[0]; dird[192]=bfs_i[1];
      int head=0, tail=1, ec=0, timec=0;
      for (int t=0;t<Tn;t++){
        int v = sv[t], bix = sb[t];
        int active = (tail>head)?1:0;
        int h = (head<=Tn)? head : Tn;
        int u = qarr[h];
        int is_stop = (v==NLl)?1:0;
        int pop = active & is_stop;
        int doe = active & (is_stop^1);
        ctrl[t] = make_int2(u | (doe<<8) | (pop<<9) | (active<<10) | (timec<<16), v | (bix<<8));
        if (doe){
          if (tail<=Tn) qarr[tail]=v;
          if (ec<192){ dirs[ec]=u; dird[ec]=v; dirs[ec+1]=v; dird[ec+1]=u; }
        }
        head+=pop; tail+=doe; ec+=2*doe; timec+=doe;
      }
      Sout[0]=ec/2;
    }
    __syncthreads();
    // ---- phase 0.5: rec outputs (parallel over t) ----
    if (tid < Tn){
      int2 c=ctrl[tid];
      rec[tid]=c.x&255; rec[Tn+tid]=c.y&255; rec[2*Tn+tid]=(c.y>>8)&3;
      rec[3*Tn+tid]=(c.x>>10)&1; rec[4*Tn+tid]=(c.x>>8)&1; rec[5*Tn+tid]=(c.x>>16)&255;
    }
    __syncthreads();
    // ---- phase A: per-lane val/closed/adj recurrence; 1 packed LDS read/iter ----
    if (tid < 64){
      const int l = tid;
      int labv = (l<N1)? slab[l] : (NAn-1);
      float val;
      switch(labv){
        case 0: val=4.f; break; case 1: val=1.f; break; case 2: val=3.f; break;
        case 3: val=1.f; break; case 4: val=2.f; break; case 5: val=1.f; break;
        case 6: val=5.f; break; case 7: val=1.f; break; case 8: val=6.f; break;
        case 9: val=1.f; break; default: val=1000.f; break;
      }
      if (l>=N1) val=0.f;
      int closed=0;
      unsigned long long adjm=0ull;
      #pragma unroll 4
      for (int t=0;t<Tn;t++){
        int2 c=ctrl[t];
        int u=c.x&255, doe=(c.x>>8)&1, pop=(c.x>>9)&1;
        int v=c.y&255, bix=(c.y>>8)&3;
        float base = (val<1.f || closed || ((adjm>>u)&1ull)) ? NEGf : 0.f;
        if (l==u) base=NEGf;
        if (l<N1) baseB[t][l]=base;
        if (l==u) valuA[t]=val;
        if (l==v) valvA[t]=val;
        if (doe){
          float dec = (bix==0)?1.f:(bix==1)?2.f:(bix==2)?3.f:1.5f;
          if (l==u){ val-=dec; adjm |= (1ull<<v); }
          if (l==v){ val-=dec; adjm |= (1ull<<u); }
        }
        if (pop && l==u) closed=1;
      }
    }
    __syncthreads();
    // ---- phase B: finalize m/e outputs ----
    {
      const int lane=tid&63, wv=tid>>6;
      for (int t=wv; t<Tn; t+=4){
        float valu=valuA[t], valv=valvA[t];
        int v=sv[t], bix=sb[t];
        if (lane<N1){
          float mnou = (valu<1.f)? NEGf : baseB[t][lane];
          float m = mnou;
          if (lane==v) m=0.f;
          if (lane==NLl) m=0.f;
          m_arr[t*N1+lane]=m;
        }
        if (lane<4){
          float mnv = (valu<1.f)? NEGf : baseB[t][v];
          float mv = fminf(valu,valv);
          float e;
          if (mv<=0.f) e=NEGf;
          else if (mv<=1.f) e=((lane==1)||(lane==2))?NEGf:0.f;
          else if (mv<=2.f) e=(lane==2)?NEGf:0.f;
          else e=0.f;
          if (mnv <= NEGf*0.5f) e=NEGf;
          if (lane==bix) e=0.f;
          e_arr[t*4+lane]=e;
        }
      }
    }
    return;
  }

  if (bid == 1){
    // ---------- ligand GCN mean (collapsed, vectorized) ----------
    __shared__ float sW[15*Dn];
    __shared__ __align__(16) float sagg[NLl][16];
    __shared__ float ow[NLl];
    __shared__ float rs[Dn];
    __shared__ float sdinv[NLl];
    __shared__ int sdeg[NLl];
    __shared__ int ses[ELl], sed[ELl];
    __shared__ int slab2[NLl];
    if (tid<NLl){ sdeg[tid]=1; slab2[tid]=lab_in[tid]; }
    for (int i=tid;i<NLl*16;i+=256) sagg[i>>4][i&15]=0.f;
    for (int i=tid;i<15*Dn;i+=256) sW[i]=Wl1[i];
    __syncthreads();
    if (tid<ELl){ ses[tid]=srcl[tid]; sed[tid]=dstl[tid]; atomicAdd(&sdeg[dstl[tid]],1); }
    __syncthreads();
    if (tid<NLl) sdinv[tid]=rsqrtf((float)sdeg[tid]);
    __syncthreads();
    if (tid<NLl){
      float dv=sdinv[tid];
      ow[tid]=dv;
      for (int q=0;q<4;q++) sagg[tid][q]=xg[tid*4+q]*dv;
      sagg[tid][4+slab2[tid]]=dv;
    }
    __syncthreads();
    if (tid<ELl){
      int s=ses[tid], d=sed[tid];
      float dvs=sdinv[s];
      for (int q=0;q<4;q++) atomicAdd(&sagg[d][q], xg[s*4+q]*dvs);
      atomicAdd(&sagg[d][4+slab2[s]], dvs);
      atomicAdd(&ow[s], sdinv[d]);
    }
    __syncthreads();
    {
      int c=tid;
      float wcol[16];
      #pragma unroll
      for (int q=0;q<15;q++) wcol[q]=sW[q*Dn+c];
      wcol[15]=0.f;
      float b=bl1[c];
      float rsum=0.f;
      for (int d=0;d<NLl;d++){
        const float4* ar=(const float4*)sagg[d];
        float4 x0=ar[0],x1=ar[1],x2=ar[2],x3=ar[3];
        float a=0.f;
        a=fmaf(x0.x,wcol[0],a); a=fmaf(x0.y,wcol[1],a); a=fmaf(x0.z,wcol[2],a); a=fmaf(x0.w,wcol[3],a);
        a=fmaf(x1.x,wcol[4],a); a=fmaf(x1.y,wcol[5],a); a=fmaf(x1.z,wcol[6],a); a=fmaf(x1.w,wcol[7],a);
        a=fmaf(x2.x,wcol[8],a); a=fmaf(x2.y,wcol[9],a); a=fmaf(x2.z,wcol[10],a); a=fmaf(x2.w,wcol[11],a);
        a=fmaf(x3.x,wcol[12],a); a=fmaf(x3.y,wcol[13],a); a=fmaf(x3.z,wcol[14],a);
        float h=fmaxf(sdinv[d]*a + b, 0.f);
        rsum = fmaf(sdinv[d]*ow[d], h, rsum);
      }
      rs[c]=rsum*(1.0f/48.0f);
    }
    __syncthreads();
    {
      int c=tid;
      float a=0.f;
      for (int k=0;k<Dn;k++) a=fmaf(rs[k], Wl2[(size_t)k*Dn+c], a);
      zl_mean[c]=a+bl2[c];
    }
    return;
  }

  {
    // ---------- pre: P = Wd2 @ [wg2 | Whu | Whv | Whh] : one k per wave ----------
    const int lane = tid&63, wv = tid>>6;
    const int k = (bid-2)*4 + wv;
    float pg=0.f;
    float4 pu=make_float4(0,0,0,0), pv=make_float4(0,0,0,0), ph=make_float4(0,0,0,0);
    for (int q=0;q<4;q++){
      int n = lane + 64*q;
      float w = Wd2[(size_t)k*Dn+n];
      pg = fmaf(w, Wg[524+n], pg);
      float4 a=*(const float4*)&Wh[(size_t)(257+n)*4];
      float4 b=*(const float4*)&Wh[(size_t)(524+n)*4];
      float4 c=*(const float4*)&Wh[(size_t)(791+n)*4];
      pu.x=fmaf(w,a.x,pu.x); pu.y=fmaf(w,a.y,pu.y); pu.z=fmaf(w,a.z,pu.z); pu.w=fmaf(w,a.w,pu.w);
      pv.x=fmaf(w,b.x,pv.x); pv.y=fmaf(w,b.y,pv.y); pv.z=fmaf(w,b.z,pv.z); pv.w=fmaf(w,b.w,pv.w);
      ph.x=fmaf(w,c.x,ph.x); ph.y=fmaf(w,c.y,ph.y); ph.z=fmaf(w,c.z,ph.z); ph.w=fmaf(w,c.w,ph.w);
    }
    for (int off=32; off>0; off>>=1){
      pg += __shfl_xor(pg,off);
      pu.x+=__shfl_xor(pu.x,off); pu.y+=__shfl_xor(pu.y,off); pu.z+=__shfl_xor(pu.z,off); pu.w+=__shfl_xor(pu.w,off);
      pv.x+=__shfl_xor(pv.x,off); pv.y+=__shfl_xor(pv.y,off); pv.z+=__shfl_xor(pv.z,off); pv.w+=__shfl_xor(pv.w,off);
      ph.x+=__shfl_xor(ph.x,off); ph.y+=__shfl_xor(ph.y,off); ph.z+=__shfl_xor(ph.z,off); ph.w+=__shfl_xor(ph.w,off);
    }
    if (lane==0){
      float* o = Pm + k*PC;
      o[0]=pg; o[1]=pu.x; o[2]=pu.y; o[3]=pu.z; o[4]=pu.w;
      o[5]=pv.x; o[6]=pv.y; o[7]=pv.z; o[8]=pv.w;
      o[9]=ph.x; o[10]=ph.y; o[11]=ph.z; o[12]=ph.w;
    }
    return;
  }
}

// ================= k_fuse: staged matvec + weighted rowsum (round-6 form) =================

__global__ __launch_bounds__(256) void k_fuse(const float* __restrict__ xp, const float* __restrict__ xagg,
    const int* __restrict__ deg, const float* __restrict__ odegw,
    const float* __restrict__ Wp1, const float* __restrict__ bp1, float* __restrict__ zr){
  __shared__ float sx[CHN][16];
  __shared__ float sc[CHN];
  int tid = threadIdx.x;
  int base = blockIdx.x*CHN;
  float wcol[15];
  for (int k=0;k<15;k++) wcol[k]=Wp1[k*Dn+tid];
  float b = bp1[tid];
  for (int i=tid;i<CHN*16;i+=256){
    int n = base+(i>>4), c = i&15;
    float v = 0.f;
    if (n<NPn && c<15){
      float dv = rsqrtf((float)(deg[n]+1));
      v = (xagg[n*16+c] + xp[n*15+c]*dv)*dv;
    }
    sx[i>>4][i&15]=v;
  }
  for (int i=tid;i<CHN;i+=256){
    int n = base+i;
    float dv = (n<NPn)? rsqrtf((float)(deg[n]+1)) : 0.f;
    sc[i] = (n<NPn)? dv*(odegw[n]+dv) : 0.f;
  }
  __syncthreads();
  float acc = 0.f;
  int lim = (NPn-base < CHN)? (NPn-base) : CHN;
  for (int i=0;i<lim;i++){
    float d0 = b;
    for (int k=0;k<15;k++) d0 = fmaf(sx[i][k], wcol[k], d0);
    acc = fmaf(sc[i], fmaxf(d0,0.f), acc);
  }
  atomicAdd(&zr[tid], acc);
}

// ================= k_dcp: decoder state + per-step PARTIALS =================

__global__ __launch_bounds__(256) void k_dcp(const int* __restrict__ Sp, const int* __restrict__ dirs,
    const int* __restrict__ dird, const int* __restrict__ lab_idx,
    const float* __restrict__ Wd1, const float* __restrict__ bd1,
    const float* __restrict__ Pm, const int* __restrict__ rec,
    const float* __restrict__ m_arr, const float* __restrict__ e_arr,
    const float* __restrict__ Wg, const float* __restrict__ Wh,
    float* __restrict__ spart){
  int k = blockIdx.x;
  if (k > Sp[0]) return;
  __shared__ float sW[11*Dn];
  __shared__ float sP[Dn*PC];
  __shared__ float hT[Dn*N1];
  __shared__ float cnt[N1*11];
  __shared__ float y1[YN];
  __shared__ float za[YN];
  __shared__ float sdinv[N1];
  __shared__ int sdeg[N1];
  __shared__ int se[192], sd[192];
  __shared__ int slab[N1];
  __shared__ int srec[6*Tn];
  int tid=threadIdx.x;
  int ecnt = (k==0)?1:(2*k);
  int base = (k==0)?192:0;
  if (tid<N1){ sdeg[tid]=1; slab[tid]=lab_idx[tid]; }
  for (int i=tid;i<N1*11;i+=256) cnt[i]=0.f;
  for (int i=tid;i<11*Dn;i+=256) sW[i]=Wd1[i];
  for (int i=tid;i<Dn*PC;i+=256) sP[i]=Pm[i];
  for (int i=tid;i<6*Tn;i+=256) srec[i]=rec[i];
  __syncthreads();
  if (tid<ecnt){ se[tid]=dirs[base+tid]; sd[tid]=dird[base+tid]; atomicAdd(&sdeg[sd[tid]],1); }
  __syncthreads();
  if (tid<N1) sdinv[tid]=rsqrtf((float)sdeg[tid]);
  __syncthreads();
  if (tid<N1) cnt[tid*11+slab[tid]] = sdinv[tid];
  __syncthreads();
  if (tid<ecnt) atomicAdd(&cnt[sd[tid]*11+slab[se[tid]]], sdinv[se[tid]]);
  __syncthreads();
  {
    int c=tid;
    float wreg[11];
    for (int a=0;a<11;a++) wreg[a]=sW[a*Dn+c];
    float b=bd1[c];
    for (int r=0;r<N1;r++){
      float s=0.f;
      for (int a=0;a<11;a++) s=fmaf(cnt[r*11+a], wreg[a], s);
      hT[c*N1+r]=fmaxf(sdinv[r]*s + b, 0.f);
    }
  }
  __syncthreads();
  for (int idx=tid; idx<YN; idx+=256){
    int r=idx/PC, j=idx-r*PC;
    float acc=0.f;
    for (int c=0;c<Dn;c++) acc=fmaf(hT[c*N1+r], sP[c*PC+j], acc);
    y1[idx]=acc;
    za[idx]=sdinv[r]*acc;
  }
  __syncthreads();
  for (int i=tid; i<ecnt*PC; i+=256){
    int e=i/PC, j=i-e*PC;
    atomicAdd(&za[sd[e]*PC+j], sdinv[se[e]]*y1[se[e]*PC+j]);
  }
  __syncthreads();
  for (int idx=tid; idx<YN; idx+=256){
    int r=idx/PC;
    za[idx]=sdinv[r]*za[idx];
  }
  __syncthreads();
  if (tid>=64) return;
  const int lane=tid;
  for (int t=0;t<Tn;t++){
    if (!srec[3*Tn+t] || srec[5*Tn+t]!=k) continue;
    const int u=srec[t], v=srec[Tn+t], doe=srec[4*Tn+t];
    float g = -INFINITY;
    float4 hm = make_float4(0,0,0,0);
    if (lane<N1){
      const float* zrow = za + lane*PC;
      g = zrow[0] + Wg[780+slab[lane]] + m_arr[t*N1+lane];
      hm.x=zrow[9]; hm.y=zrow[10]; hm.z=zrow[11]; hm.w=zrow[12];
    }
    float gv = __shfl(g, v);
    float gM = g;
    for (int off=32; off>0; off>>=1) gM = fmaxf(gM, __shfl_xor(gM, off));
    float ex = (lane<N1)? expf(g-gM) : 0.f;
    float gS = ex;
    for (int off=32; off>0; off>>=1){
      gS += __shfl_xor(gS, off);
      hm.x+=__shfl_xor(hm.x,off); hm.y+=__shfl_xor(hm.y,off);
      hm.z+=__shfl_xor(hm.z,off); hm.w+=__shfl_xor(hm.w,off);
    }
    if (lane==0){
      spart[t*5] = gv - gM - logf(gS);
      if (doe){
        const int lu=slab[u], lv=slab[v];
        const float tf=(float)k;
        for (int j=0;j<4;j++){
          float hmj = (j==0)?hm.x:(j==1)?hm.y:(j==2)?hm.z:hm.w;
          spart[t*5+1+j] = tf*Wh[j] + Wh[(513+lu)*4+j] + Wh[(780+lv)*4+j]
               + za[u*PC+1+j] + za[v*PC+5+j] + hmj*(1.0f/49.0f) + e_arr[4*t+j];
        }
      }
    }
  }
}

// ================= k_final: z_pocket GEMV + hconst + finish logp =================

__global__ __launch_bounds__(256) void k_final(const float* __restrict__ zr, const float* __restrict__ Wp2,
    const float* __restrict__ bp2, const float* __restrict__ zl, const float* __restrict__ lm,
    const float* __restrict__ b2, const float* __restrict__ Wh, const float* __restrict__ bh,
    const int* __restrict__ rec, const float* __restrict__ spart, float* __restrict__ out){
  __shared__ float sr[Dn];
  __shared__ float zp[Dn];
  __shared__ float hc4s[4];
  __shared__ float red[Tn];
  int tid=threadIdx.x;
  sr[tid]=zr[tid]*(1.0f/30000.0f);
  __syncthreads();
  float a=0.f;
  for (int k=0;k<Dn;k++) a=fmaf(sr[k],Wp2[(size_t)k*Dn+tid],a);
  zp[tid]=a+bp2[tid];
  __syncthreads();
  if (tid<64){
    int lane=tid;
    float4 h=make_float4(0,0,0,0);
    for (int q=0;q<4;q++){
      int n=lane+64*q;
      float4 w1=*(const float4*)&Wh[(size_t)(1+n)*4];
      float4 w2=*(const float4*)&Wh[(size_t)(1058+n)*4];
      float4 wu=*(const float4*)&Wh[(size_t)(257+n)*4];
      float4 wv=*(const float4*)&Wh[(size_t)(524+n)*4];
      float4 wh=*(const float4*)&Wh[(size_t)(791+n)*4];
      float zpn=zp[n], zln=zl[n], bn=b2[n];
      h.x += zpn*w1.x + zln*w2.x + bn*(wu.x+wv.x+wh.x);
      h.y += zpn*w1.y + zln*w2.y + bn*(wu.y+wv.y+wh.y);
      h.z += zpn*w1.z + zln*w2.z + bn*(wu.z+wv.z+wh.z);
      h.w += zpn*w1.w + zln*w2.w + bn*(wu.w+wv.w+wh.w);
    }
    if (lane<NAn){
      float4 wa=*(const float4*)&Wh[(size_t)(1047+lane)*4];
      float4 wb=*(const float4*)&Wh[(size_t)(1314+lane)*4];
      float aa=lm[lane], bb=lm[NAn+lane];
      h.x += aa*wa.x + bb*wb.x; h.y += aa*wa.y + bb*wb.y;
      h.z += aa*wa.z + bb*wb.z; h.w += aa*wa.w + bb*wb.w;
    }
    for (int off=32; off>0; off>>=1){
      h.x+=__shfl_xor(h.x,off); h.y+=__shfl_xor(h.y,off);
      h.z+=__shfl_xor(h.z,off); h.w+=__shfl_xor(h.w,off);
    }
    if (lane==0){
      hc4s[0]=h.x+bh[0]; hc4s[1]=h.y+bh[1]; hc4s[2]=h.z+bh[2]; hc4s[3]=h.w+bh[3];
    }
  }
  __syncthreads();
  if (tid<Tn){
    int t=tid;
    float res=0.f;
    if (rec[3*Tn+t]){
      res = spart[t*5];
      if (rec[4*Tn+t]){
        int bidx = rec[2*Tn+t];
        float h0=spart[t*5+1]+hc4s[0];
        float h1=spart[t*5+2]+hc4s[1];
        float h2=spart[t*5+3]+hc4s[2];
        float h3=spart[t*5+4]+hc4s[3];
        float M=fmaxf(fmaxf(h0,h1),fmaxf(h2,h3));
        float se2=expf(h0-M)+expf(h1-M)+expf(h2-M)+expf(h3-M);
        float hb=(bidx==0)?h0:(bidx==1)?h1:(bidx==2)?h2:h3;
        res += hb - M - logf(se2);
      }
    }
    red[t]=res;
  }
  __syncthreads();
  if (tid==0){
    float s=0.f;
    for (int t=0;t<Tn;t++) s+=red[t];
    out[0]=s;
  }
}

// ================= launch =================

extern "C" void kernel_launch(void* const* d_in, const int* in_sizes, int n_in,
                              void* d_out, int out_size, void* d_ws, size_t ws_size,
                              hipStream_t stream){
  const float* x_p      =(const float*)d_in[0];
  const int*   src_p    =(const int*)d_in[1];
  const int*   dst_p    =(const int*)d_in[2];
  const float* x_l_geom =(const float*)d_in[3];
  const int*   x_l_label=(const int*)d_in[4];
  const int*   src_l    =(const int*)d_in[5];
  const int*   dst_l    =(const int*)d_in[6];
  const int*   bfs_index=(const int*)d_in[7];
  const int*   bfs_bond =(const int*)d_in[8];
  const float* Wp1=(const float*)d_in[9];
  const float* bp1=(const float*)d_in[10];
  const float* Wp2=(const float*)d_in[11];
  const float* bp2=(const float*)d_in[12];
  const float* Wl1=(const float*)d_in[13];
  const float* bl1=(const float*)d_in[14];
  const float* Wl2=(const float*)d_in[15];
  const float* bl2=(const float*)d_in[16];
  const float* Wd1=(const float*)d_in[17];
  const float* bd1=(const float*)d_in[18];
  const float* Wd2=(const float*)d_in[19];
  const float* bd2=(const float*)d_in[20];
  const float* Wg =(const float*)d_in[23];
  const float* Wh =(const float*)d_in[25];
  const float* bh =(const float*)d_in[26];

  char* w=(char*)d_ws;
  size_t off=0;
  auto alloc=[&](size_t bytes)->char*{ char* p=w+off; off=(off+bytes+255)&~((size_t)255); return p; };
  // ---- contiguous zero-init region ----
  int*   deg    =(int*)alloc((size_t)NPn*4);
  float* odegw  =(float*)alloc((size_t)NPn*4);
  float* xagg   =(float*)alloc((size_t)NPn*16*4);
  float* zr     =(float*)alloc(Dn*4);
  size_t zero_span = off;
  // ---- rest (fully written before read) ----
  float* zl_mean=(float*)alloc(Dn*4);
  float* Pm     =(float*)alloc(Dn*PC*4);
  float* m_arr  =(float*)alloc((size_t)Tn*N1*4);
  float* e_arr  =(float*)alloc((size_t)Tn*4*4);
  int*   rec    =(int*)alloc((size_t)6*Tn*4);
  int*   dirs   =(int*)alloc(194*4);
  int*   dird   =(int*)alloc(194*4);
  int*   lab_idx=(int*)alloc(N1*4);
  float* lab_means=(float*)alloc(2*NAn*4);
  int*   Sval   =(int*)alloc(4);
  float* spart  =(float*)alloc((size_t)Tn*5*4);
  (void)in_sizes;(void)n_in;(void)ws_size;(void)out_size;

  hipMemsetAsync(d_ws, 0, zero_span, stream);

  // deg atomics (prerequisite for xagg scaling)
  k_deg<<<(EPn+255)/256, 256, 0, stream>>>(dst_p, deg);
  // mega: sim (b0) | lig (b1) | pre (b2..65) | xagg (b66..30065) — straggler overlaps atomic storm
  k_mega<<<66 + EPn*16/256, 256, 0, stream>>>(
      src_p, dst_p, x_p, deg, xagg, odegw,
      x_l_label, bfs_index, bfs_bond, lab_idx, lab_means, dirs, dird, m_arr, e_arr, rec, Sval,
      x_l_geom, src_l, dst_l, Wl1, bl1, Wl2, bl2, zl_mean,
      Wd2, Wg, Wh, Pm);
  // decoder states + per-step partials (needs only mega outputs)
  k_dcp<<<NSTATES,256,0,stream>>>(Sval,dirs,dird,lab_idx,Wd1,bd1,Pm,rec,m_arr,e_arr,Wg,Wh,spart);
  // pocket fused matvec + weighted rowsum
  k_fuse<<<(NPn+CHN-1)/CHN,256,0,stream>>>(x_p,xagg,deg,odegw,Wp1,bp1,zr);
  // final: z_pocket GEMV + hconst + finish 96 softmaxes + sum
  k_final<<<1,256,0,stream>>>(zr,Wp2,bp2,zl_mean,lab_means,bd2,Wh,bh,rec,spart,(float*)d_out);
}